// Round 4
// baseline (443.251 us; speedup 1.0000x reference)
//
#include <hip/hip_runtime.h>
#include <math.h>

constexpr int NSEQ = 32768;   // B*T independent sequences
constexpr int DM   = 128;
constexpr int FF   = 512;
constexpr int NLAY = 2;
constexpr int GRP  = 16;      // sequences per workgroup
constexpr int ROWS = 64;      // GRP * 4 tokens
#define EPS_LN 1e-5f

typedef __attribute__((ext_vector_type(8))) short bf16x8;
typedef __attribute__((ext_vector_type(4))) float f32x4;
typedef __attribute__((ext_vector_type(4))) unsigned short us4;

// d_ws layout (halfword offsets), weights pre-converted to bf16 in MFMA
// fragment order: frag(nt,kc,lane)[j] = W[nt*16+(lane&15)][kc*32+(lane>>4)*8+j]
constexpr int OFF_QKV = 0;        // L*24*4*512 = 98304
constexpr int OFF_WO  = 98304;    // L* 8*4*512 = 32768
constexpr int OFF_W1  = 131072;   // L*32*4*512 = 131072
constexpr int OFF_W2  = 262144;   // L* 8*16*512= 131072

__device__ __forceinline__ float bf2f(unsigned short u) {
  union { unsigned int i; float f; } v; v.i = ((unsigned int)u) << 16; return v.f;
}
__device__ __forceinline__ unsigned short f2bf(float f) {
  union { float f; unsigned int i; } v; v.f = f;
  unsigned int r = v.i + 0x7FFFu + ((v.i >> 16) & 1u);   // RNE
  return (unsigned short)(r >> 16);
}

__global__ __launch_bounds__(256)
void convert_weights(const float* __restrict__ Wqkv, const float* __restrict__ Wo,
                     const float* __restrict__ W1,  const float* __restrict__ W2,
                     unsigned short* __restrict__ wb) {
  int gid = blockIdx.x * 256 + threadIdx.x;   // one 8-elem frag per thread
  if (gid >= 49152) return;
  const float* src; int dst;
  if (gid < 12288) {                 // Wqkv: (l,nt<24,kc<4,lane)
    int lane = gid & 63; int r = gid >> 6;
    int kc = r & 3; r >>= 2;
    int nt = r % 24; int l = r / 24;
    src = Wqkv + ((size_t)(l*384 + nt*16 + (lane&15)))*128 + kc*32 + (lane>>4)*8;
    dst = OFF_QKV + gid*8;
  } else if (gid < 16384) {          // Wo: (l,nt<8,kc<4,lane)
    int g = gid - 12288;
    int lane = g & 63; int r = g >> 6;
    int kc = r & 3; r >>= 2;
    int nt = r & 7; int l = r >> 3;
    src = Wo + ((size_t)(l*128 + nt*16 + (lane&15)))*128 + kc*32 + (lane>>4)*8;
    dst = OFF_WO + g*8;
  } else if (gid < 32768) {          // W1: (l,nt<32,kc<4,lane)
    int g = gid - 16384;
    int lane = g & 63; int r = g >> 6;
    int kc = r & 3; r >>= 2;
    int nt = r % 32; int l = r / 32;
    src = W1 + ((size_t)(l*512 + nt*16 + (lane&15)))*128 + kc*32 + (lane>>4)*8;
    dst = OFF_W1 + g*8;
  } else {                           // W2: (l,nt<8,kc<16,lane), K=512
    int g = gid - 32768;
    int lane = g & 63; int r = g >> 6;
    int kc = r & 15; r >>= 4;
    int nt = r & 7; int l = r >> 3;
    src = W2 + ((size_t)(l*128 + nt*16 + (lane&15)))*512 + kc*32 + (lane>>4)*8;
    dst = OFF_W2 + g*8;
  }
  float4 a = *(const float4*)src;
  float4 b = *(const float4*)(src + 4);
  us4 h0, h1;
  h0[0]=f2bf(a.x); h0[1]=f2bf(a.y); h0[2]=f2bf(a.z); h0[3]=f2bf(a.w);
  h1[0]=f2bf(b.x); h1[1]=f2bf(b.y); h1[2]=f2bf(b.z); h1[3]=f2bf(b.w);
  *(us4*)(wb + dst)     = h0;
  *(us4*)(wb + dst + 4) = h1;
}

#define MFMA(a_, b_, c_) __builtin_amdgcn_mfma_f32_16x16x32_bf16((a_), (b_), (c_), 0, 0, 0)

// qkv row stride 388 hw: D-write bank = qd*8 + (l15>>1) mod 32 -> all 32 banks,
// 2 lanes/bank (same dword halves) = conflict-free.
constexpr int QS = 388;

// NOTE: second launch_bounds arg behaves as CUDA min-blocks-per-CU here:
// (512,4) forced a 64-VGPR cap (observed VGPR_Count=64 + ~390MB scratch spill
// traffic in rocprof). LDS (67KB) pins residency at 2 blocks/CU anyway, so
// declare 2 -> 128-VGPR cap, no spills.
__global__ __launch_bounds__(512, 2)
void mixer_kernel(const float* __restrict__ z0, const float* __restrict__ z1,
                  const float* __restrict__ z2, const float* __restrict__ clstok,
                  const float* __restrict__ bqkv, const float* __restrict__ bo,
                  const float* __restrict__ b1,  const float* __restrict__ b2,
                  const float* __restrict__ ln1g, const float* __restrict__ ln1b,
                  const float* __restrict__ ln2g, const float* __restrict__ ln2b,
                  const unsigned short* __restrict__ wb,
                  float* __restrict__ out)
{
  // ~67 KB LDS -> 2 blocks/CU; 8 waves/block -> 4 waves/SIMD.
  __shared__ unsigned short sxb[ROWS][136];   // bf16 A-operand (x, or attn-o)
  __shared__ union {
    unsigned short qkv[ROWS][QS];             // qkv bf16 (cols 0..383)
    float otmp[ROWS][132];                    // proj / ffn output fp32
    unsigned short h[ROWS][264];              // gelu(h) chunk bf16 (F=256)
  } u;

  const int tid  = threadIdx.x;
  const int wv   = tid >> 6;        // 0..7
  const int lane = tid & 63;
  const int l15  = lane & 15;
  const int qd   = lane >> 4;
  const int seq0 = blockIdx.x * GRP;
  const int mrow = tid >> 3;        // master row 0..63
  const int mseg = (tid & 7) * 16;  // master col base

  float xm[16];                     // fp32 residual master (registers)

  // ---------------- init: load x, mirror bf16 to sxb ----------------
  {
    int s = mrow >> 2, t = mrow & 3;
    const float* src = (t == 0) ? (clstok + mseg)
        : ((t == 1 ? z0 : t == 2 ? z1 : z2) + (size_t)(seq0 + s) * DM + mseg);
    #pragma unroll
    for (int j4 = 0; j4 < 4; ++j4) {
      float4 v = *(const float4*)(src + j4 * 4);
      xm[j4*4+0] = v.x; xm[j4*4+1] = v.y; xm[j4*4+2] = v.z; xm[j4*4+3] = v.w;
      us4 hv; hv[0]=f2bf(v.x); hv[1]=f2bf(v.y); hv[2]=f2bf(v.z); hv[3]=f2bf(v.w);
      *(us4*)&sxb[mrow][mseg + j4 * 4] = hv;
    }
  }
  __syncthreads();

  const bf16x8* wq = ((const bf16x8*)wb) + OFF_QKV / 8;
  const bf16x8* wo = ((const bf16x8*)wb) + OFF_WO  / 8;
  const bf16x8* w1 = ((const bf16x8*)wb) + OFF_W1  / 8;
  const bf16x8* w2 = ((const bf16x8*)wb) + OFF_W2  / 8;

  // LN over 128 cols: 8 lanes per row, shfl_xor(1,2,4). Reads u.otmp + xm,
  // updates xm and sxb.
  auto ln_step = [&](const float* gp, const float* bp) {
    float v[16]; float sum = 0.f, sumsq = 0.f;
    #pragma unroll
    for (int j4 = 0; j4 < 4; ++j4) {
      float4 o4 = *(const float4*)&u.otmp[mrow][mseg + j4 * 4];
      float t0;
      t0 = xm[j4*4+0] + o4.x; v[j4*4+0] = t0; sum += t0; sumsq += t0*t0;
      t0 = xm[j4*4+1] + o4.y; v[j4*4+1] = t0; sum += t0; sumsq += t0*t0;
      t0 = xm[j4*4+2] + o4.z; v[j4*4+2] = t0; sum += t0; sumsq += t0*t0;
      t0 = xm[j4*4+3] + o4.w; v[j4*4+3] = t0; sum += t0; sumsq += t0*t0;
    }
    sum   += __shfl_xor(sum, 1);   sum   += __shfl_xor(sum, 2);   sum   += __shfl_xor(sum, 4);
    sumsq += __shfl_xor(sumsq, 1); sumsq += __shfl_xor(sumsq, 2); sumsq += __shfl_xor(sumsq, 4);
    float mu  = sum * (1.0f / 128.0f);
    float var = sumsq * (1.0f / 128.0f) - mu * mu;
    float rs  = rsqrtf(var + EPS_LN);
    #pragma unroll
    for (int j4 = 0; j4 < 4; ++j4) {
      float4 g4 = *(const float4*)(gp + mseg + j4 * 4);
      float4 b4 = *(const float4*)(bp + mseg + j4 * 4);
      us4 xb; float xn;
      xn = (v[j4*4+0]-mu)*rs*g4.x + b4.x; xm[j4*4+0] = xn; xb[0] = f2bf(xn);
      xn = (v[j4*4+1]-mu)*rs*g4.y + b4.y; xm[j4*4+1] = xn; xb[1] = f2bf(xn);
      xn = (v[j4*4+2]-mu)*rs*g4.z + b4.z; xm[j4*4+2] = xn; xb[2] = f2bf(xn);
      xn = (v[j4*4+3]-mu)*rs*g4.w + b4.w; xm[j4*4+3] = xn; xb[3] = f2bf(xn);
      *(us4*)&sxb[mrow][mseg + j4 * 4] = xb;
    }
  };

  for (int l = 0; l < NLAY; ++l) {
    // ========== QKV: u.qkv[64][384] = x*Wqkv^T + b; wave does 3 n-tiles =====
    #pragma unroll
    for (int nn = 0; nn < 3; ++nn) {
      int n = wv + nn * 8;
      const bf16x8* wp = wq + (size_t)((l * 24 + n) * 4) * 64 + lane;
      bf16x8 bw0 = wp[0], bw1 = wp[64], bw2 = wp[128], bw3 = wp[192];
      float bias = bqkv[l * 384 + n * 16 + l15];
      #pragma unroll
      for (int m = 0; m < 4; ++m) {
        f32x4 acc = { bias, bias, bias, bias };
        acc = MFMA(*(const bf16x8*)&sxb[m*16+l15][ 0 + qd*8], bw0, acc);
        acc = MFMA(*(const bf16x8*)&sxb[m*16+l15][32 + qd*8], bw1, acc);
        acc = MFMA(*(const bf16x8*)&sxb[m*16+l15][64 + qd*8], bw2, acc);
        acc = MFMA(*(const bf16x8*)&sxb[m*16+l15][96 + qd*8], bw3, acc);
        #pragma unroll
        for (int ri = 0; ri < 4; ++ri)
          u.qkv[m*16 + qd*4 + ri][n*16 + l15] = f2bf(acc[ri]);
      }
    }
    __syncthreads();

    // ===== attention: 512 threads, one per (seq, head, token); K/V streamed =====
    {
      int s  = tid >> 5;          // 0..15
      int hh = (tid >> 2) & 7;    // 0..7
      int tt = tid & 3;           // 0..3
      int r0 = s * 4, c0 = hh * 16;
      float qf[16];
      #pragma unroll
      for (int p = 0; p < 4; ++p) {
        us4 qq = *(const us4*)&u.qkv[r0 + tt][c0 + p * 4];
        #pragma unroll
        for (int j = 0; j < 4; ++j) qf[p*4+j] = bf2f(qq[j]);
      }
      float sc[4];
      #pragma unroll
      for (int uu = 0; uu < 4; ++uu) {       // stream K rows
        float d0 = 0.f;
        #pragma unroll
        for (int p = 0; p < 4; ++p) {
          us4 kk = *(const us4*)&u.qkv[r0 + uu][128 + c0 + p * 4];
          #pragma unroll
          for (int j = 0; j < 4; ++j) d0 += qf[p*4+j] * bf2f(kk[j]);
        }
        sc[uu] = d0 * 0.25f;                 // 1/sqrt(dh=16)
      }
      float mx = fmaxf(fmaxf(sc[0], sc[1]), fmaxf(sc[2], sc[3]));
      float ee[4];
      ee[0] = __expf(sc[0]-mx); ee[1] = __expf(sc[1]-mx);
      ee[2] = __expf(sc[2]-mx); ee[3] = __expf(sc[3]-mx);
      float inv = 1.0f / (ee[0]+ee[1]+ee[2]+ee[3]);
      ee[0]*=inv; ee[1]*=inv; ee[2]*=inv; ee[3]*=inv;
      float of[16];
      #pragma unroll
      for (int j = 0; j < 16; ++j) of[j] = 0.f;
      #pragma unroll
      for (int uu = 0; uu < 4; ++uu) {       // stream V rows
        #pragma unroll
        for (int p = 0; p < 4; ++p) {
          us4 vv = *(const us4*)&u.qkv[r0 + uu][256 + c0 + p * 4];
          #pragma unroll
          for (int j = 0; j < 4; ++j) of[p*4+j] += ee[uu] * bf2f(vv[j]);
        }
      }
      // sxb writes don't conflict with u.qkv reads; next barrier orders proj.
      #pragma unroll
      for (int p = 0; p < 4; ++p) {
        us4 ov;
        #pragma unroll
        for (int j = 0; j < 4; ++j) ov[j] = f2bf(of[p*4+j]);
        *(us4*)&sxb[r0 + tt][c0 + p*4] = ov;   // o -> A operand for proj
      }
    }
    __syncthreads();

    // ========== proj: u.otmp = o*Wo^T + bo (fp32); wave does 1 n-tile ======
    {
      int n = wv;
      const bf16x8* wp = wo + (size_t)((l * 8 + n) * 4) * 64 + lane;
      bf16x8 bw0 = wp[0], bw1 = wp[64], bw2 = wp[128], bw3 = wp[192];
      float bias = bo[l * DM + n * 16 + l15];
      #pragma unroll
      for (int m = 0; m < 4; ++m) {
        f32x4 acc = { bias, bias, bias, bias };
        acc = MFMA(*(const bf16x8*)&sxb[m*16+l15][ 0 + qd*8], bw0, acc);
        acc = MFMA(*(const bf16x8*)&sxb[m*16+l15][32 + qd*8], bw1, acc);
        acc = MFMA(*(const bf16x8*)&sxb[m*16+l15][64 + qd*8], bw2, acc);
        acc = MFMA(*(const bf16x8*)&sxb[m*16+l15][96 + qd*8], bw3, acc);
        #pragma unroll
        for (int ri = 0; ri < 4; ++ri)
          u.otmp[m*16 + qd*4 + ri][n*16 + l15] = acc[ri];
      }
    }
    __syncthreads();

    ln_step(ln1g + l * DM, ln1b + l * DM);     // x = LN(x + attn)
    __syncthreads();

    // ========== FFN: 2 chunks of F=256 ==========
    f32x4 acc2[4];
    {
      float bias = b2[l * DM + wv * 16 + l15];
      #pragma unroll
      for (int m = 0; m < 4; ++m) {
        acc2[m][0] = bias; acc2[m][1] = bias; acc2[m][2] = bias; acc2[m][3] = bias;
      }
    }
    for (int fc = 0; fc < 2; ++fc) {
      // FFN1: wave does 2 n-tiles of this chunk
      #pragma unroll
      for (int nn = 0; nn < 2; ++nn) {
        int nl = wv + nn * 8;                  // 0..15 within chunk
        int n  = fc * 16 + nl;                 // 0..31
        const bf16x8* wp = w1 + (size_t)((l * 32 + n) * 4) * 64 + lane;
        bf16x8 bw0 = wp[0], bw1 = wp[64], bw2 = wp[128], bw3 = wp[192];
        float bias = b1[l * FF + n * 16 + l15];
        #pragma unroll
        for (int m = 0; m < 4; ++m) {
          f32x4 acc = { bias, bias, bias, bias };
          acc = MFMA(*(const bf16x8*)&sxb[m*16+l15][ 0 + qd*8], bw0, acc);
          acc = MFMA(*(const bf16x8*)&sxb[m*16+l15][32 + qd*8], bw1, acc);
          acc = MFMA(*(const bf16x8*)&sxb[m*16+l15][64 + qd*8], bw2, acc);
          acc = MFMA(*(const bf16x8*)&sxb[m*16+l15][96 + qd*8], bw3, acc);
          #pragma unroll
          for (int ri = 0; ri < 4; ++ri) {
            float xg = acc[ri];
            float g  = 0.5f * xg * (1.0f + erff(xg * 0.70710678118f));  // exact gelu
            u.h[m*16 + qd*4 + ri][nl*16 + l15] = f2bf(g);
          }
        }
      }
      __syncthreads();
      // FFN2: wave does n-tile wv; two half-batches of 4 kc (register pressure)
      #pragma unroll
      for (int half = 0; half < 2; ++half) {
        const bf16x8* wp = w2 + (size_t)((l * 8 + wv) * 16 + fc * 8 + half * 4) * 64 + lane;
        bf16x8 bw[4];
        #pragma unroll
        for (int c = 0; c < 4; ++c) bw[c] = wp[c * 64];
        #pragma unroll
        for (int m = 0; m < 4; ++m)
          #pragma unroll
          for (int c = 0; c < 4; ++c)
            acc2[m] = MFMA(*(const bf16x8*)&u.h[m*16+l15][(half*4+c)*32 + qd*8], bw[c], acc2[m]);
      }
      __syncthreads();
    }
    // dump ff output (fp32) for LN2
    #pragma unroll
    for (int m = 0; m < 4; ++m)
      #pragma unroll
      for (int ri = 0; ri < 4; ++ri)
        u.otmp[m*16 + qd*4 + ri][wv*16 + l15] = acc2[m][ri];
    __syncthreads();

    ln_step(ln2g + l * DM, ln2b + l * DM);     // x = LN(x + ff)
    __syncthreads();
  }

  // ---------------- output: CLS rows ----------------
  if ((mrow & 3) == 0) {
    float* dst = out + (size_t)(seq0 + (mrow >> 2)) * DM + mseg;
    #pragma unroll
    for (int j4 = 0; j4 < 4; ++j4) {
      float4 v = { xm[j4*4+0], xm[j4*4+1], xm[j4*4+2], xm[j4*4+3] };
      *(float4*)(dst + j4 * 4) = v;
    }
  }
}

extern "C" void kernel_launch(void* const* d_in, const int* in_sizes, int n_in,
                              void* d_out, int out_size, void* d_ws, size_t ws_size,
                              hipStream_t stream) {
  const float* z0   = (const float*)d_in[0];
  const float* z1   = (const float*)d_in[1];
  const float* z2   = (const float*)d_in[2];
  const float* cls  = (const float*)d_in[3];
  const float* Wqkv = (const float*)d_in[4];
  const float* bqkv = (const float*)d_in[5];
  const float* Wo   = (const float*)d_in[6];
  const float* bo   = (const float*)d_in[7];
  const float* W1   = (const float*)d_in[8];
  const float* b1   = (const float*)d_in[9];
  const float* W2   = (const float*)d_in[10];
  const float* b2   = (const float*)d_in[11];
  const float* l1g  = (const float*)d_in[12];
  const float* l1b  = (const float*)d_in[13];
  const float* l2g  = (const float*)d_in[14];
  const float* l2b  = (const float*)d_in[15];
  float* outp = (float*)d_out;
  unsigned short* wbf = (unsigned short*)d_ws;

  hipLaunchKernelGGL(convert_weights, dim3(192), dim3(256), 0, stream,
                     Wqkv, Wo, W1, W2, wbf);
  hipLaunchKernelGGL(mixer_kernel, dim3(NSEQ / GRP), dim3(512), 0, stream,
                     z0, z1, z2, cls, bqkv, bo, b1, b2,
                     l1g, l1b, l2g, l2b, wbf, outp);
}

// Round 5
// 373.520 us; speedup vs baseline: 1.1867x; 1.1867x over previous
//
#include <hip/hip_runtime.h>
#include <math.h>

constexpr int NSEQ = 32768;   // B*T independent sequences
constexpr int DM   = 128;
constexpr int FF   = 512;
constexpr int NLAY = 2;
constexpr int GRP  = 8;       // sequences per workgroup (4 waves, 32 rows)
constexpr int ROWS = 32;      // GRP * 4 tokens
#define EPS_LN 1e-5f

typedef __attribute__((ext_vector_type(8))) short bf16x8;
typedef __attribute__((ext_vector_type(4))) float f32x4;
typedef __attribute__((ext_vector_type(4))) unsigned short us4;

// d_ws layout (halfword offsets), weights pre-converted to bf16 in MFMA
// fragment order: frag(nt,kc,lane)[j] = W[nt*16+(lane&15)][kc*32+(lane>>4)*8+j]
constexpr int OFF_QKV = 0;        // L*24*4*512 = 98304
constexpr int OFF_WO  = 98304;    // L* 8*4*512 = 32768
constexpr int OFF_W1  = 131072;   // L*32*4*512 = 131072
constexpr int OFF_W2  = 262144;   // L* 8*16*512= 131072

__device__ __forceinline__ float bf2f(unsigned short u) {
  union { unsigned int i; float f; } v; v.i = ((unsigned int)u) << 16; return v.f;
}
__device__ __forceinline__ unsigned short f2bf(float f) {
  union { float f; unsigned int i; } v; v.f = f;
  unsigned int r = v.i + 0x7FFFu + ((v.i >> 16) & 1u);   // RNE
  return (unsigned short)(r >> 16);
}

__global__ __launch_bounds__(256)
void convert_weights(const float* __restrict__ Wqkv, const float* __restrict__ Wo,
                     const float* __restrict__ W1,  const float* __restrict__ W2,
                     unsigned short* __restrict__ wb) {
  int gid = blockIdx.x * 256 + threadIdx.x;   // one 8-elem frag per thread
  if (gid >= 49152) return;
  const float* src; int dst;
  if (gid < 12288) {                 // Wqkv: (l,nt<24,kc<4,lane)
    int lane = gid & 63; int r = gid >> 6;
    int kc = r & 3; r >>= 2;
    int nt = r % 24; int l = r / 24;
    src = Wqkv + ((size_t)(l*384 + nt*16 + (lane&15)))*128 + kc*32 + (lane>>4)*8;
    dst = OFF_QKV + gid*8;
  } else if (gid < 16384) {          // Wo: (l,nt<8,kc<4,lane)
    int g = gid - 12288;
    int lane = g & 63; int r = g >> 6;
    int kc = r & 3; r >>= 2;
    int nt = r & 7; int l = r >> 3;
    src = Wo + ((size_t)(l*128 + nt*16 + (lane&15)))*128 + kc*32 + (lane>>4)*8;
    dst = OFF_WO + g*8;
  } else if (gid < 32768) {          // W1: (l,nt<32,kc<4,lane)
    int g = gid - 16384;
    int lane = g & 63; int r = g >> 6;
    int kc = r & 3; r >>= 2;
    int nt = r % 32; int l = r / 32;
    src = W1 + ((size_t)(l*512 + nt*16 + (lane&15)))*128 + kc*32 + (lane>>4)*8;
    dst = OFF_W1 + g*8;
  } else {                           // W2: (l,nt<8,kc<16,lane), K=512
    int g = gid - 32768;
    int lane = g & 63; int r = g >> 6;
    int kc = r & 15; r >>= 4;
    int nt = r & 7; int l = r >> 3;
    src = W2 + ((size_t)(l*128 + nt*16 + (lane&15)))*512 + kc*32 + (lane>>4)*8;
    dst = OFF_W2 + g*8;
  }
  float4 a = *(const float4*)src;
  float4 b = *(const float4*)(src + 4);
  us4 h0, h1;
  h0[0]=f2bf(a.x); h0[1]=f2bf(a.y); h0[2]=f2bf(a.z); h0[3]=f2bf(a.w);
  h1[0]=f2bf(b.x); h1[1]=f2bf(b.y); h1[2]=f2bf(b.z); h1[3]=f2bf(b.w);
  *(us4*)(wb + dst)     = h0;
  *(us4*)(wb + dst + 4) = h1;
}

#define MFMA(a_, b_, c_) __builtin_amdgcn_mfma_f32_16x16x32_bf16((a_), (b_), (c_), 0, 0, 0)

constexpr int QS = 388;   // qkv row stride (hw) — spreads D-writes over all banks

// 256-thread blocks: residency quantum = 4 waves. LDS ~33.5KB -> 4 blocks/CU
// possible; __launch_bounds__(256,4) = 128-reg cap under BOTH arg semantics
// (4 blocks/CU or 4 waves/EU -> identical). Round-4 lesson: 512-thr blocks
// at >128 total regs/wave dropped to 1 block/CU (24% occ).
__global__ __launch_bounds__(256, 4)
void mixer_kernel(const float* __restrict__ z0, const float* __restrict__ z1,
                  const float* __restrict__ z2, const float* __restrict__ clstok,
                  const float* __restrict__ bqkv, const float* __restrict__ bo,
                  const float* __restrict__ b1,  const float* __restrict__ b2,
                  const float* __restrict__ ln1g, const float* __restrict__ ln1b,
                  const float* __restrict__ ln2g, const float* __restrict__ ln2b,
                  const unsigned short* __restrict__ wb,
                  float* __restrict__ out)
{
  __shared__ unsigned short sxb[ROWS][136];   // bf16 A-operand (x, or attn-o)
  __shared__ union {
    unsigned short qkv[ROWS][QS];             // qkv bf16 (cols 0..383)
    float otmp[ROWS][132];                    // proj / ffn output fp32
    unsigned short h[ROWS][264];              // gelu(h) chunk bf16 (F=256)
  } u;

  const int tid  = threadIdx.x;
  const int wv   = tid >> 6;        // 0..3
  const int lane = tid & 63;
  const int l15  = lane & 15;
  const int qd   = lane >> 4;
  const int seq0 = blockIdx.x * GRP;
  const int mrow = tid >> 3;        // master row 0..31
  const int mseg = (tid & 7) * 16;  // master col base

  float xm[16];                     // fp32 residual master (registers)

  // ---------------- init: load x, mirror bf16 to sxb ----------------
  {
    int s = mrow >> 2, t = mrow & 3;
    const float* src = (t == 0) ? (clstok + mseg)
        : ((t == 1 ? z0 : t == 2 ? z1 : z2) + (size_t)(seq0 + s) * DM + mseg);
    #pragma unroll
    for (int j4 = 0; j4 < 4; ++j4) {
      float4 v = *(const float4*)(src + j4 * 4);
      xm[j4*4+0] = v.x; xm[j4*4+1] = v.y; xm[j4*4+2] = v.z; xm[j4*4+3] = v.w;
      us4 hv; hv[0]=f2bf(v.x); hv[1]=f2bf(v.y); hv[2]=f2bf(v.z); hv[3]=f2bf(v.w);
      *(us4*)&sxb[mrow][mseg + j4 * 4] = hv;
    }
  }
  __syncthreads();

  const bf16x8* wq = ((const bf16x8*)wb) + OFF_QKV / 8;
  const bf16x8* wo = ((const bf16x8*)wb) + OFF_WO  / 8;
  const bf16x8* w1 = ((const bf16x8*)wb) + OFF_W1  / 8;
  const bf16x8* w2 = ((const bf16x8*)wb) + OFF_W2  / 8;

  // LN over 128 cols: 8 lanes per row, shfl_xor(1,2,4). Reads u.otmp + xm,
  // updates xm and sxb.
  auto ln_step = [&](const float* gp, const float* bp) {
    float v[16]; float sum = 0.f, sumsq = 0.f;
    #pragma unroll
    for (int j4 = 0; j4 < 4; ++j4) {
      float4 o4 = *(const float4*)&u.otmp[mrow][mseg + j4 * 4];
      float t0;
      t0 = xm[j4*4+0] + o4.x; v[j4*4+0] = t0; sum += t0; sumsq += t0*t0;
      t0 = xm[j4*4+1] + o4.y; v[j4*4+1] = t0; sum += t0; sumsq += t0*t0;
      t0 = xm[j4*4+2] + o4.z; v[j4*4+2] = t0; sum += t0; sumsq += t0*t0;
      t0 = xm[j4*4+3] + o4.w; v[j4*4+3] = t0; sum += t0; sumsq += t0*t0;
    }
    sum   += __shfl_xor(sum, 1);   sum   += __shfl_xor(sum, 2);   sum   += __shfl_xor(sum, 4);
    sumsq += __shfl_xor(sumsq, 1); sumsq += __shfl_xor(sumsq, 2); sumsq += __shfl_xor(sumsq, 4);
    float mu  = sum * (1.0f / 128.0f);
    float var = sumsq * (1.0f / 128.0f) - mu * mu;
    float rs  = rsqrtf(var + EPS_LN);
    #pragma unroll
    for (int j4 = 0; j4 < 4; ++j4) {
      float4 g4 = *(const float4*)(gp + mseg + j4 * 4);
      float4 b4 = *(const float4*)(bp + mseg + j4 * 4);
      us4 xb; float xn;
      xn = (v[j4*4+0]-mu)*rs*g4.x + b4.x; xm[j4*4+0] = xn; xb[0] = f2bf(xn);
      xn = (v[j4*4+1]-mu)*rs*g4.y + b4.y; xm[j4*4+1] = xn; xb[1] = f2bf(xn);
      xn = (v[j4*4+2]-mu)*rs*g4.z + b4.z; xm[j4*4+2] = xn; xb[2] = f2bf(xn);
      xn = (v[j4*4+3]-mu)*rs*g4.w + b4.w; xm[j4*4+3] = xn; xb[3] = f2bf(xn);
      *(us4*)&sxb[mrow][mseg + j4 * 4] = xb;
    }
  };

  for (int l = 0; l < NLAY; ++l) {
    // ===== QKV: u.qkv[32][384] = x*Wqkv^T + b; wave does 6 n-tiles x 2 m ====
    for (int nn = 0; nn < 6; ++nn) {
      int n = wv + nn * 4;
      const bf16x8* wp = wq + (size_t)((l * 24 + n) * 4) * 64 + lane;
      bf16x8 bw0 = wp[0], bw1 = wp[64], bw2 = wp[128], bw3 = wp[192];
      float bias = bqkv[l * 384 + n * 16 + l15];
      #pragma unroll
      for (int m = 0; m < 2; ++m) {
        f32x4 acc = { bias, bias, bias, bias };
        acc = MFMA(*(const bf16x8*)&sxb[m*16+l15][ 0 + qd*8], bw0, acc);
        acc = MFMA(*(const bf16x8*)&sxb[m*16+l15][32 + qd*8], bw1, acc);
        acc = MFMA(*(const bf16x8*)&sxb[m*16+l15][64 + qd*8], bw2, acc);
        acc = MFMA(*(const bf16x8*)&sxb[m*16+l15][96 + qd*8], bw3, acc);
        #pragma unroll
        for (int ri = 0; ri < 4; ++ri)
          u.qkv[m*16 + qd*4 + ri][n*16 + l15] = f2bf(acc[ri]);
      }
    }
    __syncthreads();

    // ===== attention: 256 threads = (8 seq) x (8 head) x (4 token) ========
    {
      int s  = tid >> 5;          // 0..7
      int hh = (tid >> 2) & 7;    // 0..7
      int tt = tid & 3;           // 0..3
      int r0 = s * 4, c0 = hh * 16;
      float qf[16];
      #pragma unroll
      for (int p = 0; p < 4; ++p) {
        us4 qq = *(const us4*)&u.qkv[r0 + tt][c0 + p * 4];
        #pragma unroll
        for (int j = 0; j < 4; ++j) qf[p*4+j] = bf2f(qq[j]);
      }
      float sc[4];
      #pragma unroll
      for (int uu = 0; uu < 4; ++uu) {       // stream K rows
        float d0 = 0.f;
        #pragma unroll
        for (int p = 0; p < 4; ++p) {
          us4 kk = *(const us4*)&u.qkv[r0 + uu][128 + c0 + p * 4];
          #pragma unroll
          for (int j = 0; j < 4; ++j) d0 += qf[p*4+j] * bf2f(kk[j]);
        }
        sc[uu] = d0 * 0.25f;                 // 1/sqrt(dh=16)
      }
      float mx = fmaxf(fmaxf(sc[0], sc[1]), fmaxf(sc[2], sc[3]));
      float ee[4];
      ee[0] = __expf(sc[0]-mx); ee[1] = __expf(sc[1]-mx);
      ee[2] = __expf(sc[2]-mx); ee[3] = __expf(sc[3]-mx);
      float inv = 1.0f / (ee[0]+ee[1]+ee[2]+ee[3]);
      ee[0]*=inv; ee[1]*=inv; ee[2]*=inv; ee[3]*=inv;
      float of[16];
      #pragma unroll
      for (int j = 0; j < 16; ++j) of[j] = 0.f;
      #pragma unroll
      for (int uu = 0; uu < 4; ++uu) {       // stream V rows
        #pragma unroll
        for (int p = 0; p < 4; ++p) {
          us4 vv = *(const us4*)&u.qkv[r0 + uu][256 + c0 + p * 4];
          #pragma unroll
          for (int j = 0; j < 4; ++j) of[p*4+j] += ee[uu] * bf2f(vv[j]);
        }
      }
      // sxb writes don't alias u.qkv reads; next barrier orders proj.
      #pragma unroll
      for (int p = 0; p < 4; ++p) {
        us4 ov;
        #pragma unroll
        for (int j = 0; j < 4; ++j) ov[j] = f2bf(of[p*4+j]);
        *(us4*)&sxb[r0 + tt][c0 + p*4] = ov;   // o -> A operand for proj
      }
    }
    __syncthreads();

    // ===== proj: u.otmp = o*Wo^T + bo (fp32); wave does 2 n-tiles x 2 m ====
    #pragma unroll
    for (int ni = 0; ni < 2; ++ni) {
      int n = wv + ni * 4;
      const bf16x8* wp = wo + (size_t)((l * 8 + n) * 4) * 64 + lane;
      bf16x8 bw0 = wp[0], bw1 = wp[64], bw2 = wp[128], bw3 = wp[192];
      float bias = bo[l * DM + n * 16 + l15];
      #pragma unroll
      for (int m = 0; m < 2; ++m) {
        f32x4 acc = { bias, bias, bias, bias };
        acc = MFMA(*(const bf16x8*)&sxb[m*16+l15][ 0 + qd*8], bw0, acc);
        acc = MFMA(*(const bf16x8*)&sxb[m*16+l15][32 + qd*8], bw1, acc);
        acc = MFMA(*(const bf16x8*)&sxb[m*16+l15][64 + qd*8], bw2, acc);
        acc = MFMA(*(const bf16x8*)&sxb[m*16+l15][96 + qd*8], bw3, acc);
        #pragma unroll
        for (int ri = 0; ri < 4; ++ri)
          u.otmp[m*16 + qd*4 + ri][n*16 + l15] = acc[ri];
      }
    }
    __syncthreads();

    ln_step(ln1g + l * DM, ln1b + l * DM);     // x = LN(x + attn)
    __syncthreads();

    // ===== FFN: 2 chunks of F=256 ====
    f32x4 acc2[2][2];                          // [n-tile][m-tile], init = b2
    #pragma unroll
    for (int ni = 0; ni < 2; ++ni) {
      float bias = b2[l * DM + (wv + ni * 4) * 16 + l15];
      #pragma unroll
      for (int m = 0; m < 2; ++m) {
        acc2[ni][m][0] = bias; acc2[ni][m][1] = bias;
        acc2[ni][m][2] = bias; acc2[ni][m][3] = bias;
      }
    }
    for (int fc = 0; fc < 2; ++fc) {
      // FFN1: wave does 4 n-tiles of this chunk x 2 m
      for (int nn = 0; nn < 4; ++nn) {
        int nl = wv + nn * 4;                  // 0..15 within chunk
        int n  = fc * 16 + nl;                 // 0..31
        const bf16x8* wp = w1 + (size_t)((l * 32 + n) * 4) * 64 + lane;
        bf16x8 bw0 = wp[0], bw1 = wp[64], bw2 = wp[128], bw3 = wp[192];
        float bias = b1[l * FF + n * 16 + l15];
        #pragma unroll
        for (int m = 0; m < 2; ++m) {
          f32x4 acc = { bias, bias, bias, bias };
          acc = MFMA(*(const bf16x8*)&sxb[m*16+l15][ 0 + qd*8], bw0, acc);
          acc = MFMA(*(const bf16x8*)&sxb[m*16+l15][32 + qd*8], bw1, acc);
          acc = MFMA(*(const bf16x8*)&sxb[m*16+l15][64 + qd*8], bw2, acc);
          acc = MFMA(*(const bf16x8*)&sxb[m*16+l15][96 + qd*8], bw3, acc);
          #pragma unroll
          for (int ri = 0; ri < 4; ++ri) {
            float xg = acc[ri];
            float g  = 0.5f * xg * (1.0f + erff(xg * 0.70710678118f));  // exact gelu
            u.h[m*16 + qd*4 + ri][nl*16 + l15] = f2bf(g);
          }
        }
      }
      __syncthreads();
      // FFN2: wave does 2 n-tiles; two half-batches of 4 kc (reg pressure)
      #pragma unroll
      for (int ni = 0; ni < 2; ++ni) {
        int n = wv + ni * 4;
        #pragma unroll
        for (int half = 0; half < 2; ++half) {
          const bf16x8* wp = w2 + (size_t)((l * 8 + n) * 16 + fc * 8 + half * 4) * 64 + lane;
          bf16x8 bw[4];
          #pragma unroll
          for (int c = 0; c < 4; ++c) bw[c] = wp[c * 64];
          #pragma unroll
          for (int m = 0; m < 2; ++m)
            #pragma unroll
            for (int c = 0; c < 4; ++c)
              acc2[ni][m] = MFMA(*(const bf16x8*)&u.h[m*16+l15][(half*4+c)*32 + qd*8], bw[c], acc2[ni][m]);
        }
      }
      __syncthreads();
    }
    // dump ff output (fp32) for LN2
    #pragma unroll
    for (int ni = 0; ni < 2; ++ni) {
      int n = wv + ni * 4;
      #pragma unroll
      for (int m = 0; m < 2; ++m)
        #pragma unroll
        for (int ri = 0; ri < 4; ++ri)
          u.otmp[m*16 + qd*4 + ri][n*16 + l15] = acc2[ni][m][ri];
    }
    __syncthreads();

    ln_step(ln2g + l * DM, ln2b + l * DM);     // x = LN(x + ff)
    __syncthreads();
  }

  // ---------------- output: CLS rows ----------------
  if ((mrow & 3) == 0) {
    float* dst = out + (size_t)(seq0 + (mrow >> 2)) * DM + mseg;
    #pragma unroll
    for (int j4 = 0; j4 < 4; ++j4) {
      float4 v = { xm[j4*4+0], xm[j4*4+1], xm[j4*4+2], xm[j4*4+3] };
      *(float4*)(dst + j4 * 4) = v;
    }
  }
}

extern "C" void kernel_launch(void* const* d_in, const int* in_sizes, int n_in,
                              void* d_out, int out_size, void* d_ws, size_t ws_size,
                              hipStream_t stream) {
  const float* z0   = (const float*)d_in[0];
  const float* z1   = (const float*)d_in[1];
  const float* z2   = (const float*)d_in[2];
  const float* cls  = (const float*)d_in[3];
  const float* Wqkv = (const float*)d_in[4];
  const float* bqkv = (const float*)d_in[5];
  const float* Wo   = (const float*)d_in[6];
  const float* bo   = (const float*)d_in[7];
  const float* W1   = (const float*)d_in[8];
  const float* b1   = (const float*)d_in[9];
  const float* W2   = (const float*)d_in[10];
  const float* b2   = (const float*)d_in[11];
  const float* l1g  = (const float*)d_in[12];
  const float* l1b  = (const float*)d_in[13];
  const float* l2g  = (const float*)d_in[14];
  const float* l2b  = (const float*)d_in[15];
  float* outp = (float*)d_out;
  unsigned short* wbf = (unsigned short*)d_ws;

  hipLaunchKernelGGL(convert_weights, dim3(192), dim3(256), 0, stream,
                     Wqkv, Wo, W1, W2, wbf);
  hipLaunchKernelGGL(mixer_kernel, dim3(NSEQ / GRP), dim3(256), 0, stream,
                     z0, z1, z2, cls, bqkv, bo, b1, b2,
                     l1g, l1b, l2g, l2b, wbf, outp);
}

// Round 6
// 341.849 us; speedup vs baseline: 1.2966x; 1.0926x over previous
//
#include <hip/hip_runtime.h>
#include <math.h>

constexpr int NSEQ = 32768;   // B*T independent sequences
constexpr int DM   = 128;
constexpr int FF   = 512;
constexpr int NLAY = 2;
constexpr int GRP  = 8;       // sequences per workgroup (4 waves, 32 rows)
constexpr int ROWS = 32;      // GRP * 4 tokens
#define EPS_LN 1e-5f

typedef __attribute__((ext_vector_type(8))) short bf16x8;
typedef __attribute__((ext_vector_type(4))) float f32x4;
typedef __attribute__((ext_vector_type(4))) unsigned short us4;

// d_ws layout (halfword offsets), weights pre-converted to bf16 in MFMA
// fragment order: frag(nt,kc,lane)[j] = W[nt*16+(lane&15)][kc*32+(lane>>4)*8+j]
constexpr int OFF_QKV = 0;        // L*24*4*512 = 98304
constexpr int OFF_WO  = 98304;    // L* 8*4*512 = 32768
constexpr int OFF_W1  = 131072;   // L*32*4*512 = 131072
constexpr int OFF_W2  = 262144;   // L* 8*16*512= 131072

__device__ __forceinline__ float bf2f(unsigned short u) {
  union { unsigned int i; float f; } v; v.i = ((unsigned int)u) << 16; return v.f;
}
__device__ __forceinline__ unsigned short f2bf(float f) {
  union { float f; unsigned int i; } v; v.f = f;
  unsigned int r = v.i + 0x7FFFu + ((v.i >> 16) & 1u);   // RNE
  return (unsigned short)(r >> 16);
}

__global__ __launch_bounds__(256)
void convert_weights(const float* __restrict__ Wqkv, const float* __restrict__ Wo,
                     const float* __restrict__ W1,  const float* __restrict__ W2,
                     unsigned short* __restrict__ wb) {
  int gid = blockIdx.x * 256 + threadIdx.x;   // one 8-elem frag per thread
  if (gid >= 49152) return;
  const float* src; int dst;
  if (gid < 12288) {                 // Wqkv: (l,nt<24,kc<4,lane)
    int lane = gid & 63; int r = gid >> 6;
    int kc = r & 3; r >>= 2;
    int nt = r % 24; int l = r / 24;
    src = Wqkv + ((size_t)(l*384 + nt*16 + (lane&15)))*128 + kc*32 + (lane>>4)*8;
    dst = OFF_QKV + gid*8;
  } else if (gid < 16384) {          // Wo: (l,nt<8,kc<4,lane)
    int g = gid - 12288;
    int lane = g & 63; int r = g >> 6;
    int kc = r & 3; r >>= 2;
    int nt = r & 7; int l = r >> 3;
    src = Wo + ((size_t)(l*128 + nt*16 + (lane&15)))*128 + kc*32 + (lane>>4)*8;
    dst = OFF_WO + g*8;
  } else if (gid < 32768) {          // W1: (l,nt<32,kc<4,lane)
    int g = gid - 16384;
    int lane = g & 63; int r = g >> 6;
    int kc = r & 3; r >>= 2;
    int nt = r % 32; int l = r / 32;
    src = W1 + ((size_t)(l*512 + nt*16 + (lane&15)))*128 + kc*32 + (lane>>4)*8;
    dst = OFF_W1 + g*8;
  } else {                           // W2: (l,nt<8,kc<16,lane), K=512
    int g = gid - 32768;
    int lane = g & 63; int r = g >> 6;
    int kc = r & 15; r >>= 4;
    int nt = r & 7; int l = r >> 3;
    src = W2 + ((size_t)(l*128 + nt*16 + (lane&15)))*512 + kc*32 + (lane>>4)*8;
    dst = OFF_W2 + g*8;
  }
  float4 a = *(const float4*)src;
  float4 b = *(const float4*)(src + 4);
  us4 h0, h1;
  h0[0]=f2bf(a.x); h0[1]=f2bf(a.y); h0[2]=f2bf(a.z); h0[3]=f2bf(a.w);
  h1[0]=f2bf(b.x); h1[1]=f2bf(b.y); h1[2]=f2bf(b.z); h1[3]=f2bf(b.w);
  *(us4*)(wb + dst)     = h0;
  *(us4*)(wb + dst + 4) = h1;
}

#define MFMA(a_, b_, c_) __builtin_amdgcn_mfma_f32_16x16x32_bf16((a_), (b_), (c_), 0, 0, 0)

constexpr int QS = 388;   // qkv row stride (hw) — spreads D-writes over all banks

// Launch-bounds history (hard-won): 2nd arg = min waves per EU (HIP semantics),
// and the cap it implies (512 regs/SIMD / waves) covers VGPR+AGPR *combined*.
//   (512,4)/(256,4) -> cap 128 -> 64/64 split -> massive scratch spills.
//   (512,2) -> cap 256, clean 112 VGPR, but 8-wave blocks -> only 8 waves/CU.
// Natural demand is ~140 total -> 3 waves/EU is the operating point:
// (256,3) -> cap ~170, no spills, 3 blocks/CU = 12 waves/CU.
__global__ __launch_bounds__(256, 3)
void mixer_kernel(const float* __restrict__ z0, const float* __restrict__ z1,
                  const float* __restrict__ z2, const float* __restrict__ clstok,
                  const float* __restrict__ bqkv, const float* __restrict__ bo,
                  const float* __restrict__ b1,  const float* __restrict__ b2,
                  const float* __restrict__ ln1g, const float* __restrict__ ln1b,
                  const float* __restrict__ ln2g, const float* __restrict__ ln2b,
                  const unsigned short* __restrict__ wb,
                  float* __restrict__ out)
{
  __shared__ unsigned short sxb[ROWS][136];   // bf16 A-operand (x, or attn-o)
  __shared__ union {
    unsigned short qkv[ROWS][QS];             // qkv bf16 (cols 0..383)
    float otmp[ROWS][132];                    // proj / ffn output fp32
    unsigned short h[ROWS][264];              // gelu(h) chunk bf16 (F=256)
  } u;

  const int tid  = threadIdx.x;
  const int wv   = tid >> 6;        // 0..3
  const int lane = tid & 63;
  const int l15  = lane & 15;
  const int qd   = lane >> 4;
  const int seq0 = blockIdx.x * GRP;
  const int mrow = tid >> 3;        // master row 0..31
  const int mseg = (tid & 7) * 16;  // master col base

  float xm[16];                     // fp32 residual master (registers)

  // ---------------- init: load x, mirror bf16 to sxb ----------------
  {
    int s = mrow >> 2, t = mrow & 3;
    const float* src = (t == 0) ? (clstok + mseg)
        : ((t == 1 ? z0 : t == 2 ? z1 : z2) + (size_t)(seq0 + s) * DM + mseg);
    #pragma unroll
    for (int j4 = 0; j4 < 4; ++j4) {
      float4 v = *(const float4*)(src + j4 * 4);
      xm[j4*4+0] = v.x; xm[j4*4+1] = v.y; xm[j4*4+2] = v.z; xm[j4*4+3] = v.w;
      us4 hv; hv[0]=f2bf(v.x); hv[1]=f2bf(v.y); hv[2]=f2bf(v.z); hv[3]=f2bf(v.w);
      *(us4*)&sxb[mrow][mseg + j4 * 4] = hv;
    }
  }
  __syncthreads();

  const bf16x8* wq = ((const bf16x8*)wb) + OFF_QKV / 8;
  const bf16x8* wo = ((const bf16x8*)wb) + OFF_WO  / 8;
  const bf16x8* w1 = ((const bf16x8*)wb) + OFF_W1  / 8;
  const bf16x8* w2 = ((const bf16x8*)wb) + OFF_W2  / 8;

  // LN over 128 cols: 8 lanes per row, shfl_xor(1,2,4). Reads u.otmp + xm,
  // updates xm and sxb.
  auto ln_step = [&](const float* gp, const float* bp) {
    float v[16]; float sum = 0.f, sumsq = 0.f;
    #pragma unroll
    for (int j4 = 0; j4 < 4; ++j4) {
      float4 o4 = *(const float4*)&u.otmp[mrow][mseg + j4 * 4];
      float t0;
      t0 = xm[j4*4+0] + o4.x; v[j4*4+0] = t0; sum += t0; sumsq += t0*t0;
      t0 = xm[j4*4+1] + o4.y; v[j4*4+1] = t0; sum += t0; sumsq += t0*t0;
      t0 = xm[j4*4+2] + o4.z; v[j4*4+2] = t0; sum += t0; sumsq += t0*t0;
      t0 = xm[j4*4+3] + o4.w; v[j4*4+3] = t0; sum += t0; sumsq += t0*t0;
    }
    sum   += __shfl_xor(sum, 1);   sum   += __shfl_xor(sum, 2);   sum   += __shfl_xor(sum, 4);
    sumsq += __shfl_xor(sumsq, 1); sumsq += __shfl_xor(sumsq, 2); sumsq += __shfl_xor(sumsq, 4);
    float mu  = sum * (1.0f / 128.0f);
    float var = sumsq * (1.0f / 128.0f) - mu * mu;
    float rs  = rsqrtf(var + EPS_LN);
    #pragma unroll
    for (int j4 = 0; j4 < 4; ++j4) {
      float4 g4 = *(const float4*)(gp + mseg + j4 * 4);
      float4 b4 = *(const float4*)(bp + mseg + j4 * 4);
      us4 xb; float xn;
      xn = (v[j4*4+0]-mu)*rs*g4.x + b4.x; xm[j4*4+0] = xn; xb[0] = f2bf(xn);
      xn = (v[j4*4+1]-mu)*rs*g4.y + b4.y; xm[j4*4+1] = xn; xb[1] = f2bf(xn);
      xn = (v[j4*4+2]-mu)*rs*g4.z + b4.z; xm[j4*4+2] = xn; xb[2] = f2bf(xn);
      xn = (v[j4*4+3]-mu)*rs*g4.w + b4.w; xm[j4*4+3] = xn; xb[3] = f2bf(xn);
      *(us4*)&sxb[mrow][mseg + j4 * 4] = xb;
    }
  };

  for (int l = 0; l < NLAY; ++l) {
    // ===== QKV: u.qkv[32][384] = x*Wqkv^T + b; wave does 6 n-tiles x 2 m ====
    for (int nn = 0; nn < 6; ++nn) {
      int n = wv + nn * 4;
      const bf16x8* wp = wq + (size_t)((l * 24 + n) * 4) * 64 + lane;
      bf16x8 bw0 = wp[0], bw1 = wp[64], bw2 = wp[128], bw3 = wp[192];
      float bias = bqkv[l * 384 + n * 16 + l15];
      #pragma unroll
      for (int m = 0; m < 2; ++m) {
        f32x4 acc = { bias, bias, bias, bias };
        acc = MFMA(*(const bf16x8*)&sxb[m*16+l15][ 0 + qd*8], bw0, acc);
        acc = MFMA(*(const bf16x8*)&sxb[m*16+l15][32 + qd*8], bw1, acc);
        acc = MFMA(*(const bf16x8*)&sxb[m*16+l15][64 + qd*8], bw2, acc);
        acc = MFMA(*(const bf16x8*)&sxb[m*16+l15][96 + qd*8], bw3, acc);
        #pragma unroll
        for (int ri = 0; ri < 4; ++ri)
          u.qkv[m*16 + qd*4 + ri][n*16 + l15] = f2bf(acc[ri]);
      }
    }
    __syncthreads();

    // ===== attention: 256 threads = (8 seq) x (8 head) x (4 token) ========
    {
      int s  = tid >> 5;          // 0..7
      int hh = (tid >> 2) & 7;    // 0..7
      int tt = tid & 3;           // 0..3
      int r0 = s * 4, c0 = hh * 16;
      float qf[16];
      #pragma unroll
      for (int p = 0; p < 4; ++p) {
        us4 qq = *(const us4*)&u.qkv[r0 + tt][c0 + p * 4];
        #pragma unroll
        for (int j = 0; j < 4; ++j) qf[p*4+j] = bf2f(qq[j]);
      }
      float sc[4];
      #pragma unroll
      for (int uu = 0; uu < 4; ++uu) {       // stream K rows
        float d0 = 0.f;
        #pragma unroll
        for (int p = 0; p < 4; ++p) {
          us4 kk = *(const us4*)&u.qkv[r0 + uu][128 + c0 + p * 4];
          #pragma unroll
          for (int j = 0; j < 4; ++j) d0 += qf[p*4+j] * bf2f(kk[j]);
        }
        sc[uu] = d0 * 0.25f;                 // 1/sqrt(dh=16)
      }
      float mx = fmaxf(fmaxf(sc[0], sc[1]), fmaxf(sc[2], sc[3]));
      float ee[4];
      ee[0] = __expf(sc[0]-mx); ee[1] = __expf(sc[1]-mx);
      ee[2] = __expf(sc[2]-mx); ee[3] = __expf(sc[3]-mx);
      float inv = 1.0f / (ee[0]+ee[1]+ee[2]+ee[3]);
      ee[0]*=inv; ee[1]*=inv; ee[2]*=inv; ee[3]*=inv;
      float of[16];
      #pragma unroll
      for (int j = 0; j < 16; ++j) of[j] = 0.f;
      #pragma unroll
      for (int uu = 0; uu < 4; ++uu) {       // stream V rows
        #pragma unroll
        for (int p = 0; p < 4; ++p) {
          us4 vv = *(const us4*)&u.qkv[r0 + uu][256 + c0 + p * 4];
          #pragma unroll
          for (int j = 0; j < 4; ++j) of[p*4+j] += ee[uu] * bf2f(vv[j]);
        }
      }
      // sxb writes don't alias u.qkv reads; next barrier orders proj.
      #pragma unroll
      for (int p = 0; p < 4; ++p) {
        us4 ov;
        #pragma unroll
        for (int j = 0; j < 4; ++j) ov[j] = f2bf(of[p*4+j]);
        *(us4*)&sxb[r0 + tt][c0 + p*4] = ov;   // o -> A operand for proj
      }
    }
    __syncthreads();

    // ===== proj: u.otmp = o*Wo^T + bo (fp32); wave does 2 n-tiles x 2 m ====
    #pragma unroll
    for (int ni = 0; ni < 2; ++ni) {
      int n = wv + ni * 4;
      const bf16x8* wp = wo + (size_t)((l * 8 + n) * 4) * 64 + lane;
      bf16x8 bw0 = wp[0], bw1 = wp[64], bw2 = wp[128], bw3 = wp[192];
      float bias = bo[l * DM + n * 16 + l15];
      #pragma unroll
      for (int m = 0; m < 2; ++m) {
        f32x4 acc = { bias, bias, bias, bias };
        acc = MFMA(*(const bf16x8*)&sxb[m*16+l15][ 0 + qd*8], bw0, acc);
        acc = MFMA(*(const bf16x8*)&sxb[m*16+l15][32 + qd*8], bw1, acc);
        acc = MFMA(*(const bf16x8*)&sxb[m*16+l15][64 + qd*8], bw2, acc);
        acc = MFMA(*(const bf16x8*)&sxb[m*16+l15][96 + qd*8], bw3, acc);
        #pragma unroll
        for (int ri = 0; ri < 4; ++ri)
          u.otmp[m*16 + qd*4 + ri][n*16 + l15] = acc[ri];
      }
    }
    __syncthreads();

    ln_step(ln1g + l * DM, ln1b + l * DM);     // x = LN(x + attn)
    __syncthreads();

    // ===== FFN: 2 chunks of F=256 ====
    f32x4 acc2[2][2];                          // [n-tile][m-tile], init = b2
    #pragma unroll
    for (int ni = 0; ni < 2; ++ni) {
      float bias = b2[l * DM + (wv + ni * 4) * 16 + l15];
      #pragma unroll
      for (int m = 0; m < 2; ++m) {
        acc2[ni][m][0] = bias; acc2[ni][m][1] = bias;
        acc2[ni][m][2] = bias; acc2[ni][m][3] = bias;
      }
    }
    for (int fc = 0; fc < 2; ++fc) {
      // FFN1: wave does 4 n-tiles of this chunk x 2 m
      for (int nn = 0; nn < 4; ++nn) {
        int nl = wv + nn * 4;                  // 0..15 within chunk
        int n  = fc * 16 + nl;                 // 0..31
        const bf16x8* wp = w1 + (size_t)((l * 32 + n) * 4) * 64 + lane;
        bf16x8 bw0 = wp[0], bw1 = wp[64], bw2 = wp[128], bw3 = wp[192];
        float bias = b1[l * FF + n * 16 + l15];
        #pragma unroll
        for (int m = 0; m < 2; ++m) {
          f32x4 acc = { bias, bias, bias, bias };
          acc = MFMA(*(const bf16x8*)&sxb[m*16+l15][ 0 + qd*8], bw0, acc);
          acc = MFMA(*(const bf16x8*)&sxb[m*16+l15][32 + qd*8], bw1, acc);
          acc = MFMA(*(const bf16x8*)&sxb[m*16+l15][64 + qd*8], bw2, acc);
          acc = MFMA(*(const bf16x8*)&sxb[m*16+l15][96 + qd*8], bw3, acc);
          #pragma unroll
          for (int ri = 0; ri < 4; ++ri) {
            float xg = acc[ri];
            float g  = 0.5f * xg * (1.0f + erff(xg * 0.70710678118f));  // exact gelu
            u.h[m*16 + qd*4 + ri][nl*16 + l15] = f2bf(g);
          }
        }
      }
      __syncthreads();
      // FFN2: wave does 2 n-tiles; two half-batches of 4 kc (reg pressure)
      #pragma unroll
      for (int ni = 0; ni < 2; ++ni) {
        int n = wv + ni * 4;
        #pragma unroll
        for (int half = 0; half < 2; ++half) {
          const bf16x8* wp = w2 + (size_t)((l * 8 + n) * 16 + fc * 8 + half * 4) * 64 + lane;
          bf16x8 bw[4];
          #pragma unroll
          for (int c = 0; c < 4; ++c) bw[c] = wp[c * 64];
          #pragma unroll
          for (int m = 0; m < 2; ++m)
            #pragma unroll
            for (int c = 0; c < 4; ++c)
              acc2[ni][m] = MFMA(*(const bf16x8*)&u.h[m*16+l15][(half*4+c)*32 + qd*8], bw[c], acc2[ni][m]);
        }
      }
      __syncthreads();
    }
    // dump ff output (fp32) for LN2
    #pragma unroll
    for (int ni = 0; ni < 2; ++ni) {
      int n = wv + ni * 4;
      #pragma unroll
      for (int m = 0; m < 2; ++m)
        #pragma unroll
        for (int ri = 0; ri < 4; ++ri)
          u.otmp[m*16 + qd*4 + ri][n*16 + l15] = acc2[ni][m][ri];
    }
    __syncthreads();

    ln_step(ln2g + l * DM, ln2b + l * DM);     // x = LN(x + ff)
    __syncthreads();
  }

  // ---------------- output: CLS rows ----------------
  if ((mrow & 3) == 0) {
    float* dst = out + (size_t)(seq0 + (mrow >> 2)) * DM + mseg;
    #pragma unroll
    for (int j4 = 0; j4 < 4; ++j4) {
      float4 v = { xm[j4*4+0], xm[j4*4+1], xm[j4*4+2], xm[j4*4+3] };
      *(float4*)(dst + j4 * 4) = v;
    }
  }
}

extern "C" void kernel_launch(void* const* d_in, const int* in_sizes, int n_in,
                              void* d_out, int out_size, void* d_ws, size_t ws_size,
                              hipStream_t stream) {
  const float* z0   = (const float*)d_in[0];
  const float* z1   = (const float*)d_in[1];
  const float* z2   = (const float*)d_in[2];
  const float* cls  = (const float*)d_in[3];
  const float* Wqkv = (const float*)d_in[4];
  const float* bqkv = (const float*)d_in[5];
  const float* Wo   = (const float*)d_in[6];
  const float* bo   = (const float*)d_in[7];
  const float* W1   = (const float*)d_in[8];
  const float* b1   = (const float*)d_in[9];
  const float* W2   = (const float*)d_in[10];
  const float* b2   = (const float*)d_in[11];
  const float* l1g  = (const float*)d_in[12];
  const float* l1b  = (const float*)d_in[13];
  const float* l2g  = (const float*)d_in[14];
  const float* l2b  = (const float*)d_in[15];
  float* outp = (float*)d_out;
  unsigned short* wbf = (unsigned short*)d_ws;

  hipLaunchKernelGGL(convert_weights, dim3(192), dim3(256), 0, stream,
                     Wqkv, Wo, W1, W2, wbf);
  hipLaunchKernelGGL(mixer_kernel, dim3(NSEQ / GRP), dim3(256), 0, stream,
                     z0, z1, z2, cls, bqkv, bo, b1, b2,
                     l1g, l1b, l2g, l2b, wbf, outp);
}